// Round 12
// baseline (252.478 us; speedup 1.0000x reference)
//
#include <hip/hip_runtime.h>

// Problem constants (from reference)
#define B_     256
#define M_     64
#define T_     1200
#define FT_    10
#define K_     17
#define POOLK_ 75
#define POOLS_ 15
#define TP_    76            // pooled length
#define NSEG_  80            // segments of 15
#define FEAT_  (FT_*TP_)     // 760
#define NT_    5             // 5 MFMA tiles x 16 segments = 80
#define RPB_   4             // rows per block (same m, consecutive b)

typedef _Float16 f16;
typedef f16   f16x8 __attribute__((ext_vector_type(8)));
typedef float f32x4 __attribute__((ext_vector_type(4)));
typedef float f32x4u __attribute__((ext_vector_type(4), aligned(4)));  // 4B-aligned vec load

// Pin a 128-bit fragment in VGPRs.
#define PIN8(v) do {                                                   \
    f32x4 _t = __builtin_bit_cast(f32x4, (v));                         \
    float _a0=_t[0], _a1=_t[1], _a2=_t[2], _a3=_t[3];                  \
    asm volatile("" : "+v"(_a0), "+v"(_a1), "+v"(_a2), "+v"(_a3));     \
    _t = (f32x4){_a0,_a1,_a2,_a3};                                     \
    (v) = __builtin_bit_cast(f16x8, _t);                               \
} while (0)

// r12 = r11's segment-aligned Toeplitz MFMA, PERSISTENT over 4 rows.
// r10/r11 identical at 82us -> shared per-row init dominates: A-frags, wsm2,
// widx, lw, lin_b are row-independent (weights!) yet rebuilt by all 16384
// blocks.  r12: 4096 blocks x 4 rows (same m => same lin_w row, L1-hot);
// init built ONCE, row loop only does {B-build, 15 MFMA, reduce, epilogue}.
// Math is byte-identical to r11 (absmax must stay 2.441406e-4).
__global__ __launch_bounds__(128, 6)
void ChannelScorer_Distributed_39024072851482_kernel(
    const float* __restrict__ x,      // (B,1,M,T) -> row-major (B*M, T)
    const float* __restrict__ conv_w, // (FT,1,K) = 170
    const float* __restrict__ conv_b, // (FT,)
    const float* __restrict__ lin_w,  // (M, FEAT)
    const float* __restrict__ lin_b,  // (M,)
    float* __restrict__ out)          // (B,M,1) -> 16384
{
    __shared__ float wsm2[FT_*32];               // 1.25 KB zero-padded weights
    __shared__ float S[FT_][NSEG_];              // 3.2 KB segment sums
    __shared__ float red[2];

    const int tid = threadIdx.x;
    const int bid = blockIdx.x;
    const int m   = bid & (M_-1);                // channel: fixed per block
    const int bg  = bid >> 6;                    // 0..63: group of 4 batches

    // ---- stage zero-padded weight table (once) ----
    for (int i = tid; i < FT_*32; i += 128) {
        const int f = i >> 5, d = i & 31;
        wsm2[i] = (d < K_) ? conv_w[f*K_ + d] : 0.f;
    }
    __syncthreads();

    const int lane = tid & 63, wid = tid >> 6;   // wid = filter-half
    const int n = lane & 15, khi = lane >> 4;
    const float m3 = (khi == 3) ? 0.f : 1.f;     // drop C row 15 (next seg's u=0)

    // ---- A-frags for this wave's 5 filters: ROW-INDEPENDENT, built once ----
    f16x8 ah[5], al[5];
    float bf[5];
    #pragma unroll
    for (int fi = 0; fi < 5; ++fi) {
        const int f = wid*5 + fi;
        const float* wf = &wsm2[f*32];
        #pragma unroll
        for (int j = 0; j < 8; ++j) {
            const float wv = wf[(8*khi + j - n) & 31];   // wrap -> zero tail
            const f16 h = (f16)wv;
            ah[fi][j] = h; al[fi][j] = (f16)(wv - (float)h);
        }
        PIN8(ah[fi]); PIN8(al[fi]);
        bf[fi] = conv_b[f];                      // wave-uniform -> s_load
    }

    const int ebase = 15*n + 8*khi - 8;
    const float* lw = lin_w + (size_t)m * FEAT_; // constant per block (L1-hot)
    const float lbm = lin_b[m];

    // ---- row loop: 4 batches of the same channel ----
    #pragma unroll 1
    for (int r = 0; r < RPB_; ++r) {
        const int row = ((bg*RPB_ + r) << 6) | m;
        const float* xr = x + (size_t)row * T_;

        // conv: tile-outer (B live one iteration), filter-inner (r11 schedule)
        #pragma unroll
        for (int t = 0; t < NT_; ++t) {
            const int e0 = 240*t + ebase;
            float v[8];
            bool safe = (t >= 1 && t <= 3);      // e0 in [232,961], +7 < 1200
            if (t == 0) safe = (e0 >= 0);        // only lane n=0,khi=0 unsafe
            if (t == 4) safe = (e0 + 7 < T_);    // only n=15,khi>=2 unsafe
            if (safe) {
                f32x4u a = *(const f32x4u*)(xr + e0);
                f32x4u b = *(const f32x4u*)(xr + e0 + 4);
                v[0]=a[0]; v[1]=a[1]; v[2]=a[2]; v[3]=a[3];
                v[4]=b[0]; v[5]=b[1]; v[6]=b[2]; v[7]=b[3];
            } else {
                #pragma unroll
                for (int j = 0; j < 8; ++j) {
                    const int e = e0 + j;
                    v[j] = ((unsigned)e < (unsigned)T_) ? xr[e] : 0.f;
                }
            }
            f16x8 bh, bl;
            #pragma unroll
            for (int j = 0; j < 8; ++j) {
                const f16 h = (f16)v[j];
                bh[j] = h; bl[j] = (f16)(v[j] - (float)h);
            }

            #pragma unroll
            for (int fi = 0; fi < 5; ++fi) {
                f32x4 acc = {bf[fi], bf[fi], bf[fi], bf[fi]};
                acc = __builtin_amdgcn_mfma_f32_16x16x32_f16(ah[fi], bh, acc, 0, 0, 0);
                acc = __builtin_amdgcn_mfma_f32_16x16x32_f16(ah[fi], bl, acc, 0, 0, 0);
                acc = __builtin_amdgcn_mfma_f32_16x16x32_f16(al[fi], bh, acc, 0, 0, 0);
                float p = fmaf(acc[0],acc[0], fmaf(acc[1],acc[1],
                          fmaf(acc[2],acc[2], acc[3]*acc[3]*m3)));
                p += __shfl_xor(p, 16, 64);      // sum over khi groups
                p += __shfl_xor(p, 32, 64);
                if (lane < 16) S[wid*5 + fi][16*t + lane] = p;  // seg g = 16t+n
            }
        }
        __syncthreads();

        // pool(5 segs) -> log -> dot with lin_w[m,:]
        float partial = 0.f;
        for (int i = tid; i < FEAT_; i += 128) { // 6 iters
            const int f = i / TP_;
            const int p = i - f * TP_;
            const float* Sp = &S[f][p];
            float v = (Sp[0] + Sp[1] + Sp[2] + Sp[3] + Sp[4]) * (1.0f/POOLK_);
            v = fmaxf(v, 1e-10f);
            partial = fmaf(__logf(v), lw[i], partial);
        }

        // block reduction (2 waves)
        #pragma unroll
        for (int off = 32; off > 0; off >>= 1)
            partial += __shfl_down(partial, off, 64);
        if ((tid & 63) == 0) red[wid] = partial;
        __syncthreads();
        if (tid == 0)
            out[row] = red[0] + red[1] + lbm;
        __syncthreads();                         // S and red reused next row
    }
}

extern "C" void kernel_launch(void* const* d_in, const int* in_sizes, int n_in,
                              void* d_out, int out_size, void* d_ws, size_t ws_size,
                              hipStream_t stream) {
    const float* x      = (const float*)d_in[0];
    const float* conv_w = (const float*)d_in[1];
    const float* conv_b = (const float*)d_in[2];
    const float* lin_w  = (const float*)d_in[3];
    const float* lin_b  = (const float*)d_in[4];
    float* out = (float*)d_out;

    dim3 grid((B_ / RPB_) * M_);    // 4096 blocks: (m, 4-batch group)
    dim3 block(128);                // 2 waves
    ChannelScorer_Distributed_39024072851482_kernel<<<grid, block, 0, stream>>>(
        x, conv_w, conv_b, lin_w, lin_b, out);
}